// Round 2
// baseline (576.055 us; speedup 1.0000x reference)
//
#include <hip/hip_runtime.h>
#include <math.h>

#define N_TOKENS 32768
#define EMBED    2048
#define NEXP     64
#define TOPK     8
#define BM       64
#define BK       32
#define LSTR     36           // BK + 4 pad floats: keeps 16B alignment, breaks pow2 stride
#define D4       (EMBED / 4)

__global__ __launch_bounds__(256, 2)
void router_kernel(const float* __restrict__ x, const float* __restrict__ W,
                   const float* __restrict__ bias, float* __restrict__ out) {
  __shared__ float  xs[BM * LSTR];
  __shared__ float  ws[NEXP * LSTR];
  __shared__ double sc[BM * NEXP];   // fp64 scores for exact ranking

  const int tid = threadIdx.x;
  const int t0  = blockIdx.x * BM;
  const int ty  = tid >> 4;        // 0..15
  const int tx  = tid & 15;        // 0..15
  const int r0  = tid >> 3;        // staging row 0..31
  const int c0  = tid & 7;         // staging float4 col 0..7
  const int r1  = r0 + 32;         // second staging row 32..63

  const float4* x4 = (const float4*)x;
  const float4* W4 = (const float4*)W;

  double acc[4][4];
#pragma unroll
  for (int i = 0; i < 4; ++i)
#pragma unroll
    for (int j = 0; j < 4; ++j) acc[i][j] = 0.0;

  // prefetch chunk 0 into registers
  float4 ax0 = x4[(size_t)(t0 + r0) * D4 + c0];
  float4 ax1 = x4[(size_t)(t0 + r1) * D4 + c0];
  float4 aw0 = W4[(size_t)r0 * D4 + c0];
  float4 aw1 = W4[(size_t)r1 * D4 + c0];

  const int nch = EMBED / BK;      // 64 chunks
  for (int ch = 0; ch < nch; ++ch) {
    *(float4*)&xs[r0 * LSTR + (c0 << 2)] = ax0;
    *(float4*)&xs[r1 * LSTR + (c0 << 2)] = ax1;
    *(float4*)&ws[r0 * LSTR + (c0 << 2)] = aw0;
    *(float4*)&ws[r1 * LSTR + (c0 << 2)] = aw1;
    __syncthreads();

    if (ch + 1 < nch) {            // register prefetch of next chunk overlaps compute
      const int ko = (ch + 1) * (BK / 4) + c0;
      ax0 = x4[(size_t)(t0 + r0) * D4 + ko];
      ax1 = x4[(size_t)(t0 + r1) * D4 + ko];
      aw0 = W4[(size_t)r0 * D4 + ko];
      aw1 = W4[(size_t)r1 * D4 + ko];
    }

#pragma unroll
    for (int kk = 0; kk < BK; kk += 4) {
      float4 av4[4], bv4[4];
#pragma unroll
      for (int i = 0; i < 4; ++i)
        av4[i] = *(const float4*)&xs[(ty + 16 * i) * LSTR + kk];
#pragma unroll
      for (int j = 0; j < 4; ++j)
        bv4[j] = *(const float4*)&ws[(tx + 16 * j) * LSTR + kk];

      float aa[4][4], bb[4][4];
#pragma unroll
      for (int i = 0; i < 4; ++i) {
        aa[i][0] = av4[i].x; aa[i][1] = av4[i].y; aa[i][2] = av4[i].z; aa[i][3] = av4[i].w;
        bb[i][0] = bv4[i].x; bb[i][1] = bv4[i].y; bb[i][2] = bv4[i].z; bb[i][3] = bv4[i].w;
      }
#pragma unroll
      for (int s = 0; s < 4; ++s) {
        double ad[4], bd[4];
#pragma unroll
        for (int i = 0; i < 4; ++i) { ad[i] = (double)aa[i][s]; bd[i] = (double)bb[i][s]; }
#pragma unroll
        for (int i = 0; i < 4; ++i)
#pragma unroll
          for (int j = 0; j < 4; ++j)
            acc[i][j] = fma(ad[i], bd[j], acc[i][j]);
      }
    }
    __syncthreads();
  }

  // scores -> LDS (fp64), row = token, col = expert
#pragma unroll
  for (int i = 0; i < 4; ++i)
#pragma unroll
    for (int j = 0; j < 4; ++j)
      sc[(ty + 16 * i) * NEXP + tx + 16 * j] = acc[i][j];
  __syncthreads();

  float* rout = out;                                  // [32768, 64] f32
  float* iout = out + (size_t)N_TOKENS * NEXP;        // [32768, 8] indices AS FLOAT
  const int lane = tid & 63;
  const int wv   = tid >> 6;
  const double bl = (double)bias[lane];

  for (int tt = 0; tt < 16; ++tt) {
    const int t = wv * 16 + tt;
    const double orig = sc[t * NEXP + lane] + bl;     // lane = expert
    double cur = orig;
    double vals[8];
    int    myidx  = 0;
    double mymask = 0.0;

#pragma unroll
    for (int r = 0; r < 8; ++r) {
      double v = cur;
      int    id = lane;
#pragma unroll
      for (int s2 = 1; s2 < 64; s2 <<= 1) {
        const double ov = __shfl_xor(v, s2);
        const int    oi = __shfl_xor(id, s2);
        // max by value; exact-tie -> lower index (matches stable top_k)
        if (ov > v || (ov == v && oi < id)) { v = ov; id = oi; }
      }
      vals[r] = v;
      if (lane == r)  myidx = id;
      if (lane == id) { mymask = orig; cur = -1e300; }
    }

    // softmax over mask: 56 zeros + 8 top scores (fp64 for accuracy)
    const double m = fmax(vals[0], 0.0);
    double Z = 56.0 * exp(-m);
#pragma unroll
    for (int r = 0; r < 8; ++r) Z += exp(vals[r] - m);
    const double p = exp(mymask - m) / Z;

    rout[(size_t)(t0 + t) * NEXP + lane] = (float)p;
    if (lane < TOPK) iout[(size_t)(t0 + t) * TOPK + lane] = (float)myidx;
  }
}

extern "C" void kernel_launch(void* const* d_in, const int* in_sizes, int n_in,
                              void* d_out, int out_size, void* d_ws, size_t ws_size,
                              hipStream_t stream) {
  const float* x = (const float*)d_in[0];
  const float* W = (const float*)d_in[1];
  const float* b = (const float*)d_in[2];
  router_kernel<<<N_TOKENS / BM, 256, 0, stream>>>(x, W, b, (float*)d_out);
}

// Round 3
// 568.137 us; speedup vs baseline: 1.0139x; 1.0139x over previous
//
#include <hip/hip_runtime.h>
#include <math.h>

#define N_TOKENS 32768
#define EMBED    2048
#define NEXP     64
#define TOPK     8
#define BM       64
#define BK       64
#define D4       (EMBED / 4)     // 512 float4 per row
#define SCS      65              // sc leading-dim pad
#define THRESH   1e-4f           // fixup trigger: adjacent top-9 gap below this

typedef __attribute__((ext_vector_type(8)))  short short8;
typedef __attribute__((ext_vector_type(16))) float f32x16;

__device__ inline unsigned short bf16rne(float f) {
  unsigned int fb = __float_as_uint(f);
  return (unsigned short)((fb + 0x7FFFu + ((fb >> 16) & 1u)) >> 16);
}

// 8 fp32 -> bf16 hi (RNE) + bf16 lo (RNE of residual)
__device__ inline void cvt8(float4 a, float4 b, short8& h, short8& l) {
  float fs[8] = {a.x, a.y, a.z, a.w, b.x, b.y, b.z, b.w};
#pragma unroll
  for (int i = 0; i < 8; ++i) {
    unsigned int hr = (__float_as_uint(fs[i]) + 0x7FFFu + ((__float_as_uint(fs[i]) >> 16) & 1u)) >> 16;
    h[i] = (short)hr;
    float hf = __uint_as_float(hr << 16);
    l[i] = (short)bf16rne(fs[i] - hf);
  }
}

__global__ __launch_bounds__(256, 2)
void router_kernel(const float* __restrict__ x, const float* __restrict__ W,
                   const float* __restrict__ bias, float* __restrict__ out) {
  // LDS layout for bf16 frags: [kg (k>>3)][row][8 k] -> 16B contiguous per frag read
  __shared__ short xs_h[8 * 64 * 8], xs_l[8 * 64 * 8];
  __shared__ short ws_h[8 * 64 * 8], ws_l[8 * 64 * 8];
  __shared__ float sc[BM * SCS];
  __shared__ double s_fix[NEXP];
  __shared__ int s_list[BM];
  __shared__ int s_cnt;

  const int tid  = threadIdx.x;
  const int t0   = blockIdx.x * BM;
  const int lane = tid & 63;
  const int w    = tid >> 6;          // wave 0..3
  const int half = lane >> 5;
  const int r5   = lane & 31;
  const int tw   = (w & 1) * 32;      // wave token offset
  const int ew   = (w >> 1) * 32;     // wave expert offset

  if (tid == 0) s_cnt = 0;

  const float4* x4 = (const float4*)x;
  const float4* W4 = (const float4*)W;
  // staging assignment: lane_tok = row (token/expert), w = 16-k group
  const int stok = tid & 63;
  const float4* xrow = x4 + (size_t)(t0 + stok) * D4 + w * 4;
  const float4* wrow = W4 + (size_t)stok * D4 + w * 4;

  f32x16 acc;
#pragma unroll
  for (int i = 0; i < 16; ++i) acc[i] = 0.f;

  // prefetch chunk 0 (each thread: 64B of x row, 64B of W row)
  float4 px[4], pw[4];
#pragma unroll
  for (int i = 0; i < 4; ++i) { px[i] = xrow[i]; pw[i] = wrow[i]; }

  const int nch = EMBED / BK;   // 32
  for (int ch = 0; ch < nch; ++ch) {
    __syncthreads();            // previous compute done
    {
      short8 h0, l0, h1, l1;
      cvt8(px[0], px[1], h0, l0); cvt8(px[2], px[3], h1, l1);
      *(short8*)&xs_h[((2 * w    ) * 64 + stok) * 8] = h0;
      *(short8*)&xs_h[((2 * w + 1) * 64 + stok) * 8] = h1;
      *(short8*)&xs_l[((2 * w    ) * 64 + stok) * 8] = l0;
      *(short8*)&xs_l[((2 * w + 1) * 64 + stok) * 8] = l1;
      cvt8(pw[0], pw[1], h0, l0); cvt8(pw[2], pw[3], h1, l1);
      *(short8*)&ws_h[((2 * w    ) * 64 + stok) * 8] = h0;
      *(short8*)&ws_h[((2 * w + 1) * 64 + stok) * 8] = h1;
      *(short8*)&ws_l[((2 * w    ) * 64 + stok) * 8] = l0;
      *(short8*)&ws_l[((2 * w + 1) * 64 + stok) * 8] = l1;
    }
    __syncthreads();

    if (ch + 1 < nch) {         // prefetch next chunk, overlaps MFMA below
      const int off = (ch + 1) * (BK / 4);
#pragma unroll
      for (int i = 0; i < 4; ++i) { px[i] = xrow[off + i]; pw[i] = wrow[off + i]; }
    }

#pragma unroll
    for (int s = 0; s < 4; ++s) {     // 4 x K16 per chunk
      const int kg = s * 2 + half;
      short8 ah = *(const short8*)&xs_h[(kg * 64 + tw + r5) * 8];
      short8 al = *(const short8*)&xs_l[(kg * 64 + tw + r5) * 8];
      short8 bh = *(const short8*)&ws_h[(kg * 64 + ew + r5) * 8];
      short8 bl = *(const short8*)&ws_l[(kg * 64 + ew + r5) * 8];
      acc = __builtin_amdgcn_mfma_f32_32x32x16_bf16(ah, bh, acc, 0, 0, 0);
      acc = __builtin_amdgcn_mfma_f32_32x32x16_bf16(ah, bl, acc, 0, 0, 0);
      acc = __builtin_amdgcn_mfma_f32_32x32x16_bf16(al, bh, acc, 0, 0, 0);
    }
  }

  // C layout (32x32): col = lane&31, row = (reg&3) + 8*(reg>>2) + 4*(lane>>5)
#pragma unroll
  for (int reg = 0; reg < 16; ++reg) {
    const int row = (reg & 3) + 8 * (reg >> 2) + 4 * half;
    sc[(tw + row) * SCS + ew + r5] = acc[reg];
  }
  __syncthreads();

  float* rout = out;                               // [32768, 64] probs
  float* iout = out + (size_t)N_TOKENS * NEXP;     // [32768, 8] indices as float
  const float bias_l = bias[lane];

  for (int tt = 0; tt < 16; ++tt) {
    const int t = w * 16 + tt;
    const float orig = sc[t * SCS + lane] + bias_l;    // lane = expert
    // monotone-order packed key: value bits (low 6 cleared) | (63 - idx)
    unsigned int b = __float_as_uint(orig);
    unsigned int u = b ^ (((unsigned int)((int)b >> 31)) | 0x80000000u);
    const unsigned int key = (u & 0xFFFFFFC0u) | (63u - (unsigned int)lane);
    unsigned int cur = key;
    float fv[9];
    int myidx = 0; bool sel = false; float morig = 0.f;

#pragma unroll
    for (int r = 0; r < 9; ++r) {
      unsigned int v = cur;
#pragma unroll
      for (int s2 = 1; s2 < 64; s2 <<= 1) {
        unsigned int o = (unsigned int)__shfl_xor((int)v, s2);
        v = v > o ? v : o;
      }
      unsigned int vb = (v & 0x80000000u) ? (v ^ 0x80000000u) : ~v;
      fv[r] = __uint_as_float(vb);
      if (r < 8) {
        if (lane == r) myidx = 63 - (int)(v & 63u);
        if (cur == v) { sel = true; morig = orig; cur = 0u; }
      }
    }

    float ming = fv[0] - fv[1];
#pragma unroll
    for (int r = 1; r < 8; ++r) ming = fminf(ming, fv[r] - fv[r + 1]);

    if (ming < THRESH) {
      if (lane == 0) { int p = atomicAdd(&s_cnt, 1); s_list[p] = t; }
    } else {
      const float m = fmaxf(fv[0], 0.f);
      float Z = 56.f * expf(-m);
#pragma unroll
      for (int r = 0; r < 8; ++r) Z += expf(fv[r] - m);
      const float p = expf((sel ? morig : 0.f) - m) / Z;
      rout[(size_t)(t0 + t) * NEXP + lane] = p;
      if (lane < TOPK) iout[(size_t)(t0 + t) * TOPK + lane] = (float)myidx;
    }
  }

  __syncthreads();
  const int cnt = s_cnt;

  // fp64 fixup for ambiguous tokens (exact ordering vs f64 reference)
  for (int i = 0; i < cnt; ++i) {
    const int t = s_list[i];
    const int e = tid >> 2, sub = tid & 3;
    const float4* xr = x4 + (size_t)(t0 + t) * D4 + sub * 128;
    const float4* wr = W4 + (size_t)e * D4 + sub * 128;
    double a0 = 0.0, a1 = 0.0;
#pragma unroll 4
    for (int m4 = 0; m4 < 128; m4 += 2) {
      float4 xv = xr[m4], wv = wr[m4];
      a0 = fma((double)xv.x, (double)wv.x, a0); a0 = fma((double)xv.y, (double)wv.y, a0);
      a0 = fma((double)xv.z, (double)wv.z, a0); a0 = fma((double)xv.w, (double)wv.w, a0);
      float4 xv2 = xr[m4 + 1], wv2 = wr[m4 + 1];
      a1 = fma((double)xv2.x, (double)wv2.x, a1); a1 = fma((double)xv2.y, (double)wv2.y, a1);
      a1 = fma((double)xv2.z, (double)wv2.z, a1); a1 = fma((double)xv2.w, (double)wv2.w, a1);
    }
    double a = a0 + a1;
    a += __shfl_xor(a, 1); a += __shfl_xor(a, 2);
    if (sub == 0) s_fix[e] = a + (double)bias[e];
    __syncthreads();

    if (tid < 64) {
      const double orig = s_fix[lane];
      double cur = orig, vals[8];
      int myidx = 0; double mym = 0.0;
#pragma unroll
      for (int r = 0; r < 8; ++r) {
        double v = cur; int id = lane;
#pragma unroll
        for (int s2 = 1; s2 < 64; s2 <<= 1) {
          const double ov = __shfl_xor(v, s2);
          const int    oi = __shfl_xor(id, s2);
          if (ov > v || (ov == v && oi < id)) { v = ov; id = oi; }
        }
        vals[r] = v;
        if (lane == r)  myidx = id;
        if (lane == id) { mym = orig; cur = -1e300; }
      }
      const double m = fmax(vals[0], 0.0);
      double Z = 56.0 * exp(-m);
#pragma unroll
      for (int r = 0; r < 8; ++r) Z += exp(vals[r] - m);
      const double p = exp(mym - m) / Z;
      rout[(size_t)(t0 + t) * NEXP + lane] = (float)p;
      if (lane < TOPK) iout[(size_t)(t0 + t) * TOPK + lane] = (float)myidx;
    }
    __syncthreads();
  }
}

extern "C" void kernel_launch(void* const* d_in, const int* in_sizes, int n_in,
                              void* d_out, int out_size, void* d_ws, size_t ws_size,
                              hipStream_t stream) {
  const float* x = (const float*)d_in[0];
  const float* W = (const float*)d_in[1];
  const float* b = (const float*)d_in[2];
  router_kernel<<<N_TOKENS / BM, 256, 0, stream>>>(x, W, b, (float*)d_out);
}

// Round 4
// 558.813 us; speedup vs baseline: 1.0309x; 1.0167x over previous
//
#include <hip/hip_runtime.h>
#include <math.h>

#define N_TOKENS 32768
#define EMBED    2048
#define NEXP     64
#define TOPK     8
#define BM       64
#define BK       64
#define NCH      (EMBED / BK)     // 32
#define SCS      65
#define THRESH   1e-4f
#define WELEMS   (NEXP * EMBED)   // shorts per split-W array

typedef __attribute__((ext_vector_type(8)))  short short8;
typedef __attribute__((ext_vector_type(4)))  short short4v;
typedef __attribute__((ext_vector_type(16))) float f32x16;

__device__ __forceinline__ unsigned short bf16rne(float f) {
  unsigned int fb = __float_as_uint(f);
  return (unsigned short)((fb + 0x7FFFu + ((fb >> 16) & 1u)) >> 16);
}

__device__ __forceinline__ void cvt4(float4 f, short4v* h, short4v* l) {
  float fs[4] = {f.x, f.y, f.z, f.w};
  short4v hh, ll;
#pragma unroll
  for (int i = 0; i < 4; ++i) {
    unsigned short hr = bf16rne(fs[i]);
    hh[i] = (short)hr;
    float hf = __uint_as_float((unsigned int)hr << 16);
    ll[i] = (short)bf16rne(fs[i] - hf);
  }
  *h = hh; *l = ll;
}

// W [64,2048] fp32 -> bf16 hi/lo in MFMA B-fragment layout:
// wh[((g16*2 + khalf)*64 + n)*8 + j] = bf16(W[n][g16*16 + khalf*8 + j])
__global__ void split_w(const float* __restrict__ W, short* __restrict__ wh,
                        short* __restrict__ wl) {
  const int T = blockIdx.x * 256 + threadIdx.x;   // 0..16383
  const int n = T >> 8, kg8 = T & 255;            // kg8 = g16*2 + khalf
  const float4* W4 = (const float4*)W;
  float4 a = W4[n * 512 + kg8 * 2];
  float4 b = W4[n * 512 + kg8 * 2 + 1];
  short4v h0, l0, h1, l1;
  cvt4(a, &h0, &l0); cvt4(b, &h1, &l1);
  short* dh = &wh[(kg8 * 64 + n) * 8];
  short* dl = &wl[(kg8 * 64 + n) * 8];
  *(short4v*)dh = h0; *(short4v*)(dh + 4) = h1;
  *(short4v*)dl = l0; *(short4v*)(dl + 4) = l1;
}

__global__ __launch_bounds__(256, 2)
void router_kernel(const float* __restrict__ x, const short* __restrict__ wh,
                   const short* __restrict__ wl, const float* __restrict__ bias,
                   const float* __restrict__ Wf, float* __restrict__ out) {
  // [buf][hi/lo][kg(8k)][slot(row^kg)][8 shorts] — 32 KB, double-buffered
  __shared__ short  xs[2][2][8][64][8];
  __shared__ float  sc[BM * SCS];
  __shared__ double s_fix[NEXP];
  __shared__ int    s_list[BM];
  __shared__ int    s_cnt;

  const int tid  = threadIdx.x;
  const int t0   = blockIdx.x * BM;
  const int lane = tid & 63;
  const int w    = tid >> 6;
  const int half = lane >> 5;
  const int r5   = lane & 31;
  const int tw   = (w & 1) * 32;
  const int ew   = (w >> 1) * 32;

  if (tid == 0) s_cnt = 0;

  // coalesced staging map: 16 float4-cols x 16 row-groups
  const int c4  = tid & 15;
  const int rr  = tid >> 4;
  const int g   = c4 >> 1;       // 8-k group 0..7
  const int sub = c4 & 1;

  const float* xp = x + (size_t)(t0 + rr) * EMBED + (c4 << 2);
  const short8* Bh = (const short8*)wh;
  const short8* Bl = (const short8*)wl;
  const int boff = half * 64 + ew + r5;

  f32x16 acc;
#pragma unroll
  for (int i = 0; i < 16; ++i) acc[i] = 0.f;

  float4 px[4];
#pragma unroll
  for (int i = 0; i < 4; ++i)
    px[i] = *(const float4*)(xp + (size_t)(i * 16) * EMBED);

  for (int ch = 0; ch < NCH; ++ch) {
    // B-frags for this chunk (L2-hot, coalesced b128) — issue early
    short8 bh[4], bl[4];
#pragma unroll
    for (int s = 0; s < 4; ++s) {
      const int bi = (ch * 4 + s) * 128 + boff;
      bh[s] = Bh[bi]; bl[s] = Bl[bi];
    }
    // convert prefetched x -> LDS (swizzled, conflict-free b64 writes)
    const int buf = ch & 1;
#pragma unroll
    for (int i = 0; i < 4; ++i) {
      short4v h, l;
      cvt4(px[i], &h, &l);
      const int slot = (rr + 16 * i) ^ g;
      *(short4v*)&xs[buf][0][g][slot][sub * 4] = h;
      *(short4v*)&xs[buf][1][g][slot][sub * 4] = l;
    }
    __syncthreads();

    if (ch + 1 < NCH) {        // prefetch next chunk (coalesced), lands during MFMAs
#pragma unroll
      for (int i = 0; i < 4; ++i)
        px[i] = *(const float4*)(xp + (size_t)(i * 16) * EMBED + (ch + 1) * BK);
    }

#pragma unroll
    for (int s = 0; s < 4; ++s) {
      const int kg   = 2 * s + half;
      const int slot = (tw + r5) ^ kg;
      short8 ah = *(const short8*)&xs[buf][0][kg][slot][0];
      short8 al = *(const short8*)&xs[buf][1][kg][slot][0];
      acc = __builtin_amdgcn_mfma_f32_32x32x16_bf16(ah, bh[s], acc, 0, 0, 0);
      acc = __builtin_amdgcn_mfma_f32_32x32x16_bf16(ah, bl[s], acc, 0, 0, 0);
      acc = __builtin_amdgcn_mfma_f32_32x32x16_bf16(al, bh[s], acc, 0, 0, 0);
    }
  }

  // C layout (32x32): col = lane&31, row = (reg&3) + 8*(reg>>2) + 4*(lane>>5)
#pragma unroll
  for (int reg = 0; reg < 16; ++reg) {
    const int row = (reg & 3) + 8 * (reg >> 2) + 4 * half;
    sc[(tw + row) * SCS + ew + r5] = acc[reg];
  }
  __syncthreads();

  float* rout = out;
  float* iout = out + (size_t)N_TOKENS * NEXP;
  const float bias_l = bias[lane];

  for (int tb = 0; tb < 4; ++tb) {           // 4 batches x 4 tokens (ILP over shuffle chains)
    const int tbase = w * 16 + tb * 4;
    float orig[4]; unsigned cur[4];
#pragma unroll
    for (int i = 0; i < 4; ++i) {
      orig[i] = sc[(tbase + i) * SCS + lane] + bias_l;
      unsigned b = __float_as_uint(orig[i]);
      unsigned u = b ^ (((unsigned)((int)b >> 31)) | 0x80000000u);
      cur[i] = (u & 0xFFFFFFC0u) | (63u - (unsigned)lane);
    }
    float m[4], Z[4], ming[4], prev[4], morig[4];
    int myidx[4]; bool sel[4];
#pragma unroll
    for (int i = 0; i < 4; ++i) { sel[i] = false; morig[i] = 0.f; myidx[i] = 0; ming[i] = 1e30f; }

#pragma unroll
    for (int r = 0; r < 9; ++r) {
      unsigned v[4];
#pragma unroll
      for (int i = 0; i < 4; ++i) v[i] = cur[i];
#pragma unroll
      for (int s2 = 1; s2 < 64; s2 <<= 1) {
#pragma unroll
        for (int i = 0; i < 4; ++i) {
          unsigned o = (unsigned)__shfl_xor((int)v[i], s2);
          v[i] = v[i] > o ? v[i] : o;
        }
      }
#pragma unroll
      for (int i = 0; i < 4; ++i) {
        unsigned vb = (v[i] & 0x80000000u) ? (v[i] ^ 0x80000000u) : ~v[i];
        float fv = __uint_as_float(vb);
        if (r == 0) { m[i] = fmaxf(fv, 0.f); Z[i] = 56.f * expf(-m[i]) + expf(fv - m[i]); }
        else {
          ming[i] = fminf(ming[i], prev[i] - fv);
          if (r < 8) Z[i] += expf(fv - m[i]);
        }
        prev[i] = fv;
        if (r < 8) {
          if (lane == r) myidx[i] = 63 - (int)(v[i] & 63u);
          if (cur[i] == v[i]) { sel[i] = true; morig[i] = orig[i]; cur[i] = 0u; }
        }
      }
    }
#pragma unroll
    for (int i = 0; i < 4; ++i) {
      const int t = tbase + i;
      if (ming[i] < THRESH) {
        if (lane == 0) { int p = atomicAdd(&s_cnt, 1); s_list[p] = t; }
      } else {
        const float p = expf(morig[i] - m[i]) / Z[i];
        rout[(size_t)(t0 + t) * NEXP + lane] = p;
        if (lane < TOPK) iout[(size_t)(t0 + t) * TOPK + lane] = (float)myidx[i];
      }
    }
  }

  __syncthreads();
  const int cnt = s_cnt;
  const float4* x4 = (const float4*)x;
  const float4* W4 = (const float4*)Wf;

  for (int i = 0; i < cnt; ++i) {            // fp64 fixup for ambiguous tokens
    const int t = s_list[i];
    const int e = tid >> 2, sub2 = tid & 3;
    const float4* xr = x4 + (size_t)(t0 + t) * (EMBED / 4) + sub2 * 128;
    const float4* wr = W4 + (size_t)e * (EMBED / 4) + sub2 * 128;
    double a0 = 0.0, a1 = 0.0;
#pragma unroll 4
    for (int m4 = 0; m4 < 128; m4 += 2) {
      float4 xv = xr[m4], wv = wr[m4];
      a0 = fma((double)xv.x, (double)wv.x, a0); a0 = fma((double)xv.y, (double)wv.y, a0);
      a0 = fma((double)xv.z, (double)wv.z, a0); a0 = fma((double)xv.w, (double)wv.w, a0);
      float4 xv2 = xr[m4 + 1], wv2 = wr[m4 + 1];
      a1 = fma((double)xv2.x, (double)wv2.x, a1); a1 = fma((double)xv2.y, (double)wv2.y, a1);
      a1 = fma((double)xv2.z, (double)wv2.z, a1); a1 = fma((double)xv2.w, (double)wv2.w, a1);
    }
    double a = a0 + a1;
    a += __shfl_xor(a, 1); a += __shfl_xor(a, 2);
    if (sub2 == 0) s_fix[e] = a + (double)bias[e];
    __syncthreads();

    if (tid < 64) {
      const double orig = s_fix[lane];
      double curd = orig, vals[8];
      int myidx = 0; double mym = 0.0;
#pragma unroll
      for (int r = 0; r < 8; ++r) {
        double v = curd; int id = lane;
#pragma unroll
        for (int s2 = 1; s2 < 64; s2 <<= 1) {
          const double ov = __shfl_xor(v, s2);
          const int    oi = __shfl_xor(id, s2);
          if (ov > v || (ov == v && oi < id)) { v = ov; id = oi; }
        }
        vals[r] = v;
        if (lane == r)  myidx = id;
        if (lane == id) { mym = orig; curd = -1e300; }
      }
      const double md = fmax(vals[0], 0.0);
      double Zd = 56.0 * exp(-md);
#pragma unroll
      for (int r = 0; r < 8; ++r) Zd += exp(vals[r] - md);
      const double p = exp(mym - md) / Zd;
      rout[(size_t)(t0 + t) * NEXP + lane] = (float)p;
      if (lane < TOPK) iout[(size_t)(t0 + t) * TOPK + lane] = (float)myidx;
    }
    __syncthreads();
  }
}

extern "C" void kernel_launch(void* const* d_in, const int* in_sizes, int n_in,
                              void* d_out, int out_size, void* d_ws, size_t ws_size,
                              hipStream_t stream) {
  const float* x = (const float*)d_in[0];
  const float* W = (const float*)d_in[1];
  const float* b = (const float*)d_in[2];
  short* wh = (short*)d_ws;
  short* wl = wh + WELEMS;
  split_w<<<64, 256, 0, stream>>>(W, wh, wl);
  router_kernel<<<N_TOKENS / BM, 256, 0, stream>>>(x, wh, wl, b, W, (float*)d_out);
}

// Round 5
// 557.962 us; speedup vs baseline: 1.0324x; 1.0015x over previous
//
#include <hip/hip_runtime.h>
#include <math.h>

#define N_TOKENS 32768
#define EMBED    2048
#define NEXP     64
#define TOPK     8
#define BM       64
#define BK       64
#define NCH      (EMBED / BK)     // 32
#define SCS      65
#define THRESH   1e-4f
#define WELEMS   (NEXP * EMBED)

typedef __attribute__((ext_vector_type(8)))  short short8;
typedef __attribute__((ext_vector_type(4)))  short short4v;
typedef __attribute__((ext_vector_type(16))) float f32x16;

__device__ __forceinline__ unsigned short bf16rne(float f) {
  unsigned int fb = __float_as_uint(f);
  return (unsigned short)((fb + 0x7FFFu + ((fb >> 16) & 1u)) >> 16);
}

__device__ __forceinline__ void cvt4(float4 f, short4v* h, short4v* l) {
  float fs[4] = {f.x, f.y, f.z, f.w};
  short4v hh, ll;
#pragma unroll
  for (int i = 0; i < 4; ++i) {
    unsigned short hr = bf16rne(fs[i]);
    hh[i] = (short)hr;
    float hf = __uint_as_float((unsigned int)hr << 16);
    ll[i] = (short)bf16rne(fs[i] - hf);
  }
  *h = hh; *l = ll;
}

// W [64,2048] fp32 -> bf16 hi/lo in MFMA B-fragment layout (same as R4)
__global__ void split_w(const float* __restrict__ W, short* __restrict__ wh,
                        short* __restrict__ wl) {
  const int T = blockIdx.x * 256 + threadIdx.x;   // 0..16383
  const int n = T >> 8, kg8 = T & 255;
  const float4* W4 = (const float4*)W;
  float4 a = W4[n * 512 + kg8 * 2];
  float4 b = W4[n * 512 + kg8 * 2 + 1];
  short4v h0, l0, h1, l1;
  cvt4(a, &h0, &l0); cvt4(b, &h1, &l1);
  short* dh = &wh[(kg8 * 64 + n) * 8];
  short* dl = &wl[(kg8 * 64 + n) * 8];
  *(short4v*)dh = h0; *(short4v*)(dh + 4) = h1;
  *(short4v*)dl = l0; *(short4v*)(dl + 4) = l1;
}

__global__ __launch_bounds__(256, 4)
void router_kernel(const float* __restrict__ x, const short* __restrict__ wh,
                   const short* __restrict__ wl, const float* __restrict__ bias,
                   const float* __restrict__ Wf, float* __restrict__ out) {
  // x staged as RAW fp32 via global_load_lds, double-buffered, XOR-swizzled.
  // slot(row, c4) = (row>>4)*256 + (row&15)*16 + (c4 ^ (row&15))   [float4 units]
  __shared__ float4 lx[2][1024];     // 2 x 16 KB
  __shared__ double s_fix[NEXP];
  __shared__ int    s_list[BM];
  __shared__ int    s_cnt;
  float* sc = (float*)&lx[0][0];     // overlay: used only after the K-loop

  const int tid  = threadIdx.x;
  const int t0   = blockIdx.x * BM;
  const int lane = tid & 63;
  const int w    = tid >> 6;
  const int half = lane >> 5;
  const int r5   = lane & 31;
  const int tw   = (w & 1) * 32;
  const int ew   = (w >> 1) * 32;

  if (tid == 0) s_cnt = 0;

  const float4* x4g = (const float4*)x;
  const short8* Bh  = (const short8*)wh;
  const short8* Bl  = (const short8*)wl;
  const int boff = half * 64 + ew + r5;

  // DMA staging map: thread t covers rows (t>>4)+16i, swizzled c4 = (t&15)^(t>>4)
  const int row16 = tid >> 4;        // 0..15  (== row & 15 for all i)
  const int s4    = tid & 15;
  const int c4sw  = s4 ^ row16;
  const int wbase = (tid & 192);     // wave-uniform part of lds slot

  f32x16 acc;
#pragma unroll
  for (int i = 0; i < 16; ++i) acc[i] = 0.f;

  // issue DMA for chunk 0 -> buffer 0
#pragma unroll
  for (int i = 0; i < 4; ++i) {
    const float4* gp = x4g + (size_t)(t0 + row16 + 16 * i) * (EMBED / 4) + c4sw;
    __builtin_amdgcn_global_load_lds((const void*)gp, (void*)&lx[0][i * 256 + wbase],
                                     16, 0, 0);
  }

  // per-lane fragment read address pieces
  const int arow  = tw + r5;
  const int am    = arow & 15;
  const int abase = (arow >> 4) * 256 + am * 16;

  for (int ch = 0; ch < NCH; ++ch) {
    const int buf = ch & 1;
    __syncthreads();                 // DMA(ch) landed; all reads of buf^1 done

    if (ch + 1 < NCH) {              // DMA(ch+1) -> other buffer; drained at NEXT barrier
#pragma unroll
      for (int i = 0; i < 4; ++i) {
        const float4* gp = x4g + (size_t)(t0 + row16 + 16 * i) * (EMBED / 4)
                               + (ch + 1) * 16 + c4sw;
        __builtin_amdgcn_global_load_lds((const void*)gp,
                                         (void*)&lx[buf ^ 1][i * 256 + wbase], 16, 0, 0);
      }
    }

    // B-frags for this chunk (L2-hot, coalesced b128)
    short8 bh[4], bl[4];
#pragma unroll
    for (int s = 0; s < 4; ++s) {
      const int bi = (ch * 4 + s) * 128 + boff;
      bh[s] = Bh[bi]; bl[s] = Bl[bi];
    }

#pragma unroll
    for (int s = 0; s < 4; ++s) {
      const int c0 = s * 4 + half * 2;
      float4 fa = lx[buf][abase + (c0 ^ am)];
      float4 fb = lx[buf][abase + ((c0 + 1) ^ am)];
      short4v h0, l0, h1, l1;
      cvt4(fa, &h0, &l0); cvt4(fb, &h1, &l1);
      short8 ah, al;
#pragma unroll
      for (int j = 0; j < 4; ++j) { ah[j] = h0[j]; ah[j + 4] = h1[j];
                                    al[j] = l0[j]; al[j + 4] = l1[j]; }
      acc = __builtin_amdgcn_mfma_f32_32x32x16_bf16(ah, bh[s], acc, 0, 0, 0);
      acc = __builtin_amdgcn_mfma_f32_32x32x16_bf16(ah, bl[s], acc, 0, 0, 0);
      acc = __builtin_amdgcn_mfma_f32_32x32x16_bf16(al, bh[s], acc, 0, 0, 0);
    }
  }

  __syncthreads();                   // all MFMA LDS reads done before sc overlay

  // C layout (32x32): col = lane&31, row = (reg&3) + 8*(reg>>2) + 4*(lane>>5)
#pragma unroll
  for (int reg = 0; reg < 16; ++reg) {
    const int row = (reg & 3) + 8 * (reg >> 2) + 4 * half;
    sc[(tw + row) * SCS + ew + r5] = acc[reg];
  }
  __syncthreads();

  float* rout = out;
  float* iout = out + (size_t)N_TOKENS * NEXP;
  const float bias_l = bias[lane];

  for (int tb = 0; tb < 4; ++tb) {           // 4 batches x 4 tokens (ILP over shuffles)
    const int tbase = w * 16 + tb * 4;
    float orig[4]; unsigned cur[4];
#pragma unroll
    for (int i = 0; i < 4; ++i) {
      orig[i] = sc[(tbase + i) * SCS + lane] + bias_l;
      unsigned b = __float_as_uint(orig[i]);
      unsigned u = b ^ (((unsigned)((int)b >> 31)) | 0x80000000u);
      cur[i] = (u & 0xFFFFFFC0u) | (63u - (unsigned)lane);
    }
    float m[4], Z[4], ming[4], prev[4], morig[4];
    int myidx[4]; bool sel[4];
#pragma unroll
    for (int i = 0; i < 4; ++i) { sel[i] = false; morig[i] = 0.f; myidx[i] = 0; ming[i] = 1e30f; }

#pragma unroll
    for (int r = 0; r < 9; ++r) {
      unsigned v[4];
#pragma unroll
      for (int i = 0; i < 4; ++i) v[i] = cur[i];
#pragma unroll
      for (int s2 = 1; s2 < 64; s2 <<= 1) {
#pragma unroll
        for (int i = 0; i < 4; ++i) {
          unsigned o = (unsigned)__shfl_xor((int)v[i], s2);
          v[i] = v[i] > o ? v[i] : o;
        }
      }
#pragma unroll
      for (int i = 0; i < 4; ++i) {
        unsigned vb = (v[i] & 0x80000000u) ? (v[i] ^ 0x80000000u) : ~v[i];
        float fv = __uint_as_float(vb);
        if (r == 0) { m[i] = fmaxf(fv, 0.f); Z[i] = 56.f * expf(-m[i]) + expf(fv - m[i]); }
        else {
          ming[i] = fminf(ming[i], prev[i] - fv);
          if (r < 8) Z[i] += expf(fv - m[i]);
        }
        prev[i] = fv;
        if (r < 8) {
          if (lane == r) myidx[i] = 63 - (int)(v[i] & 63u);
          if (cur[i] == v[i]) { sel[i] = true; morig[i] = orig[i]; cur[i] = 0u; }
        }
      }
    }
#pragma unroll
    for (int i = 0; i < 4; ++i) {
      const int t = tbase + i;
      if (ming[i] < THRESH) {
        if (lane == 0) { int p = atomicAdd(&s_cnt, 1); s_list[p] = t; }
      } else {
        const float p = expf(morig[i] - m[i]) / Z[i];
        rout[(size_t)(t0 + t) * NEXP + lane] = p;
        if (lane < TOPK) iout[(size_t)(t0 + t) * TOPK + lane] = (float)myidx[i];
      }
    }
  }

  __syncthreads();
  const int cnt = s_cnt;
  const float4* W4 = (const float4*)Wf;

  for (int i = 0; i < cnt; ++i) {            // fp64 fixup for ambiguous tokens
    const int t = s_list[i];
    const int e = tid >> 2, sub2 = tid & 3;
    const float4* xr = x4g + (size_t)(t0 + t) * (EMBED / 4) + sub2 * 128;
    const float4* wr = W4 + (size_t)e * (EMBED / 4) + sub2 * 128;
    double a0 = 0.0, a1 = 0.0;
#pragma unroll 4
    for (int m4 = 0; m4 < 128; m4 += 2) {
      float4 xv = xr[m4], wv = wr[m4];
      a0 = fma((double)xv.x, (double)wv.x, a0); a0 = fma((double)xv.y, (double)wv.y, a0);
      a0 = fma((double)xv.z, (double)wv.z, a0); a0 = fma((double)xv.w, (double)wv.w, a0);
      float4 xv2 = xr[m4 + 1], wv2 = wr[m4 + 1];
      a1 = fma((double)xv2.x, (double)wv2.x, a1); a1 = fma((double)xv2.y, (double)wv2.y, a1);
      a1 = fma((double)xv2.z, (double)wv2.z, a1); a1 = fma((double)xv2.w, (double)wv2.w, a1);
    }
    double a = a0 + a1;
    a += __shfl_xor(a, 1); a += __shfl_xor(a, 2);
    if (sub2 == 0) s_fix[e] = a + (double)bias[e];
    __syncthreads();

    if (tid < 64) {
      const double orig = s_fix[lane];
      double curd = orig, vals[8];
      int myidx = 0; double mym = 0.0;
#pragma unroll
      for (int r = 0; r < 8; ++r) {
        double v = curd; int id = lane;
#pragma unroll
        for (int s2 = 1; s2 < 64; s2 <<= 1) {
          const double ov = __shfl_xor(v, s2);
          const int    oi = __shfl_xor(id, s2);
          if (ov > v || (ov == v && oi < id)) { v = ov; id = oi; }
        }
        vals[r] = v;
        if (lane == r)  myidx = id;
        if (lane == id) { mym = orig; curd = -1e300; }
      }
      const double md = fmax(vals[0], 0.0);
      double Zd = 56.0 * exp(-md);
#pragma unroll
      for (int r = 0; r < 8; ++r) Zd += exp(vals[r] - md);
      const double p = exp(mym - md) / Zd;
      rout[(size_t)(t0 + t) * NEXP + lane] = (float)p;
      if (lane < TOPK) iout[(size_t)(t0 + t) * TOPK + lane] = (float)myidx;
    }
    __syncthreads();
  }
}

extern "C" void kernel_launch(void* const* d_in, const int* in_sizes, int n_in,
                              void* d_out, int out_size, void* d_ws, size_t ws_size,
                              hipStream_t stream) {
  const float* x = (const float*)d_in[0];
  const float* W = (const float*)d_in[1];
  const float* b = (const float*)d_in[2];
  short* wh = (short*)d_ws;
  short* wl = wh + WELEMS;
  split_w<<<64, 256, 0, stream>>>(W, wh, wl);
  router_kernel<<<N_TOKENS / BM, 256, 0, stream>>>(x, wh, wl, b, W, (float*)d_out);
}

// Round 6
// 469.693 us; speedup vs baseline: 1.2264x; 1.1879x over previous
//
#include <hip/hip_runtime.h>
#include <math.h>

#define N_TOKENS 32768
#define EMBED    2048
#define NEXP     64
#define TOPK     8
#define BM       64
#define BK       64
#define NCH      (EMBED / BK)     // 32
#define SCS      65
#define THRESH   1e-4f
#define WELEMS   (NEXP * EMBED)
#define FIXGRID  1024

typedef __attribute__((ext_vector_type(8)))  short short8;
typedef __attribute__((ext_vector_type(4)))  short short4v;
typedef __attribute__((ext_vector_type(16))) float f32x16;

__device__ __forceinline__ unsigned short bf16rne(float f) {
  unsigned int fb = __float_as_uint(f);
  return (unsigned short)((fb + 0x7FFFu + ((fb >> 16) & 1u)) >> 16);
}

__device__ __forceinline__ void cvt4(float4 f, short4v* h, short4v* l) {
  float fs[4] = {f.x, f.y, f.z, f.w};
  short4v hh, ll;
#pragma unroll
  for (int i = 0; i < 4; ++i) {
    unsigned short hr = bf16rne(fs[i]);
    hh[i] = (short)hr;
    float hf = __uint_as_float((unsigned int)hr << 16);
    ll[i] = (short)bf16rne(fs[i] - hf);
  }
  *h = hh; *l = ll;
}

// W [64,2048] fp32 -> bf16 hi/lo in MFMA B-fragment layout
__global__ void split_w(const float* __restrict__ W, short* __restrict__ wh,
                        short* __restrict__ wl) {
  const int T = blockIdx.x * 256 + threadIdx.x;   // 0..16383
  const int n = T >> 8, kg8 = T & 255;
  const float4* W4 = (const float4*)W;
  float4 a = W4[n * 512 + kg8 * 2];
  float4 b = W4[n * 512 + kg8 * 2 + 1];
  short4v h0, l0, h1, l1;
  cvt4(a, &h0, &l0); cvt4(b, &h1, &l1);
  short* dh = &wh[(kg8 * 64 + n) * 8];
  short* dl = &wl[(kg8 * 64 + n) * 8];
  *(short4v*)dh = h0; *(short4v*)(dh + 4) = h1;
  *(short4v*)dl = l0; *(short4v*)(dl + 4) = l1;
}

__global__ __launch_bounds__(256, 4)
void router_kernel(const float* __restrict__ x, const short* __restrict__ wh,
                   const short* __restrict__ wl, const float* __restrict__ bias,
                   int* __restrict__ gcnt, int* __restrict__ glist,
                   float* __restrict__ out) {
  // x staged RAW fp32 via global_load_lds, double-buffered, XOR-swizzled.
  __shared__ float4 lx[2][1024];     // 2 x 16 KB
  float* sc = (float*)&lx[0][0];     // overlay: used only after the K-loop

  const int tid  = threadIdx.x;
  const int t0   = blockIdx.x * BM;
  const int lane = tid & 63;
  const int w    = tid >> 6;
  const int half = lane >> 5;
  const int r5   = lane & 31;
  const int tw   = (w & 1) * 32;
  const int ew   = (w >> 1) * 32;

  const float4* x4g = (const float4*)x;
  const short8* Bh  = (const short8*)wh;
  const short8* Bl  = (const short8*)wl;
  const int boff = half * 64 + ew + r5;

  const int row16 = tid >> 4;
  const int s4    = tid & 15;
  const int c4sw  = s4 ^ row16;
  const int wbase = (tid & 192);

  f32x16 acc;
#pragma unroll
  for (int i = 0; i < 16; ++i) acc[i] = 0.f;

#pragma unroll
  for (int i = 0; i < 4; ++i) {
    const float4* gp = x4g + (size_t)(t0 + row16 + 16 * i) * (EMBED / 4) + c4sw;
    __builtin_amdgcn_global_load_lds((const void*)gp, (void*)&lx[0][i * 256 + wbase],
                                     16, 0, 0);
  }

  const int arow  = tw + r5;
  const int am    = arow & 15;
  const int abase = (arow >> 4) * 256 + am * 16;

  for (int ch = 0; ch < NCH; ++ch) {
    const int buf = ch & 1;
    __syncthreads();

    if (ch + 1 < NCH) {
#pragma unroll
      for (int i = 0; i < 4; ++i) {
        const float4* gp = x4g + (size_t)(t0 + row16 + 16 * i) * (EMBED / 4)
                               + (ch + 1) * 16 + c4sw;
        __builtin_amdgcn_global_load_lds((const void*)gp,
                                         (void*)&lx[buf ^ 1][i * 256 + wbase], 16, 0, 0);
      }
    }

    short8 bh[4], bl[4];
#pragma unroll
    for (int s = 0; s < 4; ++s) {
      const int bi = (ch * 4 + s) * 128 + boff;
      bh[s] = Bh[bi]; bl[s] = Bl[bi];
    }

#pragma unroll
    for (int s = 0; s < 4; ++s) {
      const int c0 = s * 4 + half * 2;
      float4 fa = lx[buf][abase + (c0 ^ am)];
      float4 fb = lx[buf][abase + ((c0 + 1) ^ am)];
      short4v h0, l0, h1, l1;
      cvt4(fa, &h0, &l0); cvt4(fb, &h1, &l1);
      short8 ah, al;
#pragma unroll
      for (int j = 0; j < 4; ++j) { ah[j] = h0[j]; ah[j + 4] = h1[j];
                                    al[j] = l0[j]; al[j + 4] = l1[j]; }
      acc = __builtin_amdgcn_mfma_f32_32x32x16_bf16(ah, bh[s], acc, 0, 0, 0);
      acc = __builtin_amdgcn_mfma_f32_32x32x16_bf16(ah, bl[s], acc, 0, 0, 0);
      acc = __builtin_amdgcn_mfma_f32_32x32x16_bf16(al, bh[s], acc, 0, 0, 0);
    }
  }

  __syncthreads();

  // C layout (32x32): col = lane&31, row = (reg&3) + 8*(reg>>2) + 4*(lane>>5)
#pragma unroll
  for (int reg = 0; reg < 16; ++reg) {
    const int row = (reg & 3) + 8 * (reg >> 2) + 4 * half;
    sc[(tw + row) * SCS + ew + r5] = acc[reg];
  }
  __syncthreads();

  float* rout = out;
  float* iout = out + (size_t)N_TOKENS * NEXP;
  const float bias_l = bias[lane];

  for (int tb = 0; tb < 4; ++tb) {
    const int tbase = w * 16 + tb * 4;
    float orig[4]; unsigned cur[4];
#pragma unroll
    for (int i = 0; i < 4; ++i) {
      orig[i] = sc[(tbase + i) * SCS + lane] + bias_l;
      unsigned b = __float_as_uint(orig[i]);
      unsigned u = b ^ (((unsigned)((int)b >> 31)) | 0x80000000u);
      cur[i] = (u & 0xFFFFFFC0u) | (63u - (unsigned)lane);
    }
    float m[4], Z[4], ming[4], prev[4], morig[4];
    int myidx[4]; bool sel[4];
#pragma unroll
    for (int i = 0; i < 4; ++i) { sel[i] = false; morig[i] = 0.f; myidx[i] = 0; ming[i] = 1e30f; }

#pragma unroll
    for (int r = 0; r < 9; ++r) {
      unsigned v[4];
#pragma unroll
      for (int i = 0; i < 4; ++i) v[i] = cur[i];
#pragma unroll
      for (int s2 = 1; s2 < 64; s2 <<= 1) {
#pragma unroll
        for (int i = 0; i < 4; ++i) {
          unsigned o = (unsigned)__shfl_xor((int)v[i], s2);
          v[i] = v[i] > o ? v[i] : o;
        }
      }
#pragma unroll
      for (int i = 0; i < 4; ++i) {
        unsigned vb = (v[i] & 0x80000000u) ? (v[i] ^ 0x80000000u) : ~v[i];
        float fv = __uint_as_float(vb);
        if (r == 0) { m[i] = fmaxf(fv, 0.f); Z[i] = 56.f * expf(-m[i]) + expf(fv - m[i]); }
        else {
          ming[i] = fminf(ming[i], prev[i] - fv);
          if (r < 8) Z[i] += expf(fv - m[i]);
        }
        prev[i] = fv;
        if (r < 8) {
          if (lane == r) myidx[i] = 63 - (int)(v[i] & 63u);
          if (cur[i] == v[i]) { sel[i] = true; morig[i] = orig[i]; cur[i] = 0u; }
        }
      }
    }
#pragma unroll
    for (int i = 0; i < 4; ++i) {
      const int t = tbase + i;
      if (ming[i] < THRESH) {
        if (lane == 0) { int p = atomicAdd(gcnt, 1); glist[p] = t0 + t; }
      } else {
        const float p = expf(morig[i] - m[i]) / Z[i];
        rout[(size_t)(t0 + t) * NEXP + lane] = p;
        if (lane < TOPK) iout[(size_t)(t0 + t) * TOPK + lane] = (float)myidx[i];
      }
    }
  }
}

// Exact fp64 recompute for ambiguous tokens; one token per block-iteration.
__global__ __launch_bounds__(256, 4)
void fixup_kernel(const float* __restrict__ x, const float* __restrict__ Wf,
                  const float* __restrict__ bias, const int* __restrict__ gcnt,
                  const int* __restrict__ glist, float* __restrict__ out) {
  __shared__ float4 xsh[512];        // 8 KB x row
  __shared__ double sco[NEXP];
  const int tid  = threadIdx.x;
  const int lane = tid & 63;
  const int w    = tid >> 6;
  float* rout = out;
  float* iout = out + (size_t)N_TOKENS * NEXP;
  const int cnt = *gcnt;

  for (int j = blockIdx.x; j < cnt; j += FIXGRID) {
    const int tok = glist[j];
    const float4* xr = (const float4*)x + (size_t)tok * 512;
    xsh[tid] = xr[tid];
    xsh[tid + 256] = xr[tid + 256];
    __syncthreads();

    // wave w handles experts 16w..16w+15, lanes fully coalesced over k
    for (int i = 0; i < 16; ++i) {
      const int e = w * 16 + i;
      const float4* wr = (const float4*)Wf + (size_t)e * 512;
      double a = 0.0;
#pragma unroll
      for (int q = 0; q < 8; ++q) {
        float4 wv = wr[q * 64 + lane];     // contiguous 1 KB per instruction
        float4 xv = xsh[q * 64 + lane];
        a = fma((double)xv.x, (double)wv.x, a);
        a = fma((double)xv.y, (double)wv.y, a);
        a = fma((double)xv.z, (double)wv.z, a);
        a = fma((double)xv.w, (double)wv.w, a);
      }
#pragma unroll
      for (int s2 = 1; s2 < 64; s2 <<= 1) a += __shfl_xor(a, s2);
      if (lane == 0) sco[e] = a + (double)bias[e];
    }
    __syncthreads();

    if (w == 0) {                      // exact fp64 top-8 (R2-proven)
      const double orig = sco[lane];
      double curd = orig, vals[8];
      int myidx = 0; double mym = 0.0;
#pragma unroll
      for (int r = 0; r < 8; ++r) {
        double v = curd; int id = lane;
#pragma unroll
        for (int s2 = 1; s2 < 64; s2 <<= 1) {
          const double ov = __shfl_xor(v, s2);
          const int    oi = __shfl_xor(id, s2);
          if (ov > v || (ov == v && oi < id)) { v = ov; id = oi; }
        }
        vals[r] = v;
        if (lane == r)  myidx = id;
        if (lane == id) { mym = orig; curd = -1e300; }
      }
      const double md = fmax(vals[0], 0.0);
      double Zd = 56.0 * exp(-md);
#pragma unroll
      for (int r = 0; r < 8; ++r) Zd += exp(vals[r] - md);
      const double p = exp(mym - md) / Zd;
      rout[(size_t)tok * NEXP + lane] = (float)p;
      if (lane < TOPK) iout[(size_t)tok * TOPK + lane] = (float)myidx;
    }
    __syncthreads();
  }
}

extern "C" void kernel_launch(void* const* d_in, const int* in_sizes, int n_in,
                              void* d_out, int out_size, void* d_ws, size_t ws_size,
                              hipStream_t stream) {
  const float* x = (const float*)d_in[0];
  const float* W = (const float*)d_in[1];
  const float* b = (const float*)d_in[2];
  short* wh = (short*)d_ws;
  short* wl = wh + WELEMS;
  int* gcnt  = (int*)(wl + WELEMS);      // 1 MB offset, 4-aligned
  int* glist = gcnt + 4;                 // capacity 32768 ints

  hipMemsetAsync(gcnt, 0, 16, stream);   // d_ws is re-poisoned each launch
  split_w<<<64, 256, 0, stream>>>(W, wh, wl);
  router_kernel<<<N_TOKENS / BM, 256, 0, stream>>>(x, wh, wl, b, gcnt, glist,
                                                   (float*)d_out);
  fixup_kernel<<<FIXGRID, 256, 0, stream>>>(x, W, b, gcnt, glist, (float*)d_out);
}